// Round 12
// baseline (222.540 us; speedup 1.0000x reference)
//
#include <hip/hip_runtime.h>
#include <hip/hip_bf16.h>
#include <stdint.h>

// SelfAttention B=2,T=2048,C=1024,H=16,hd=64. Inputs fp32, output fp32.
// R23: ROOT CAUSE of R15/R16/R20 "logic" failures found: HAVE_MFMA16 is 1
// in the DEVICE pass but 0 in the HOST pass (__has_builtin of an amdgcn
// builtin on the x86 host target). Host-side #if HAVE_MFMA16 guards made
// R15/16 skip the finalize launch (absmax 0.289, bit-identical) and made
// R20 launch its 512-thread kernel with 256 threads (absmax 3.6). The
// kernel designs were never actually falsified.
// This round: R20's 8-wave j-split attn, UNCONDITIONAL 512-thread launch,
// no host-side HAVE_MFMA16 anywhere (fallback removed; gfx950 has the
// builtin — it has executed since R0). Wave (wq=w>>1, jh=w&1): q-rows
// wq*16.., j-subtiles {2jh,2jh+1}; waves 0-3 stage K, 4-7 stage V
// (verbatim R14 math); in-block wave-pair (o,l) merge via LDS at end.
// Occupancy 16 -> 32 waves/CU. Walk/balance-remap/layouts unchanged.
// gemm1 = R18, gemm2 = R19, prep = R21 (all proven).

typedef __bf16 bf16_t;
typedef __attribute__((ext_vector_type(8))) __bf16 bf16x8;
typedef __attribute__((ext_vector_type(4))) __bf16 bf16x4;
typedef __attribute__((ext_vector_type(4))) short short4v;
typedef __attribute__((ext_vector_type(4))) float f32x4;

static_assert(sizeof(bf16x8) == 16, "bf16x8 must be 16B");

// EXP2F: device-only usage; host-pass fallback value is never executed.
#if defined(__has_builtin)
#if __has_builtin(__builtin_amdgcn_exp2f)
#define EXP2F(x) __builtin_amdgcn_exp2f(x)
#endif
#endif
#ifndef EXP2F
#define EXP2F(x) exp2f(x)
#endif

// async global->LDS, 16B/lane. LDS dest = wave-uniform base + lane*16.
__device__ inline void async_copy16(const bf16_t* gsrc, bf16_t* lds_dst) {
  __builtin_amdgcn_global_load_lds(
      (const __attribute__((address_space(1))) uint32_t*)(const void*)gsrc,
      (__attribute__((address_space(3))) uint32_t*)(void*)lds_dst,
      16, 0, 0);
}

// ---------------------------------------------------------------------------
// Merged prep: blocks [0,2048) convx; [2048,5120) transpose w_qkv;
// [5120,6144) transpose w_out. Transpose: float4 read, bf16x4 write. (R21)
// ---------------------------------------------------------------------------
__global__ __launch_bounds__(256) void prep_kernel(
    const float* __restrict__ x, const float* __restrict__ wq,
    const float* __restrict__ wo, bf16_t* __restrict__ xb,
    bf16_t* __restrict__ wqkvT, bf16_t* __restrict__ woutT) {
  __shared__ bf16_t tile[32][33];
  const int bid = blockIdx.x;
  if (bid < 2048) {
    const int i = bid * 256 + threadIdx.x;  // < 524288
    const float4* s = (const float4*)x;
    float4 a = s[i * 2], b = s[i * 2 + 1];
    bf16x8 o;
    o[0] = (bf16_t)a.x; o[1] = (bf16_t)a.y; o[2] = (bf16_t)a.z; o[3] = (bf16_t)a.w;
    o[4] = (bf16_t)b.x; o[5] = (bf16_t)b.y; o[6] = (bf16_t)b.z; o[7] = (bf16_t)b.w;
    ((bf16x8*)xb)[i] = o;
    return;
  }
  const bool isq = bid < 5120;
  const int id = isq ? bid - 2048 : bid - 5120;
  const int C = isq ? 3072 : 1024;
  const int R = 1024;
  const int nbx = isq ? 96 : 32;
  const float* in = isq ? wq : wo;
  bf16_t* out = isq ? wqkvT : woutT;
  const int c0 = (id % nbx) * 32, r0 = (id / nbx) * 32;
  const int tx4 = threadIdx.x & 7;   // col group (4 cols each)
  const int ty = threadIdx.x >> 3;   // row [0,32)
  {
    const float4 ld =
        *(const float4*)&in[(size_t)(r0 + ty) * C + c0 + tx4 * 4];
    tile[ty][tx4 * 4 + 0] = (bf16_t)ld.x;
    tile[ty][tx4 * 4 + 1] = (bf16_t)ld.y;
    tile[ty][tx4 * 4 + 2] = (bf16_t)ld.z;
    tile[ty][tx4 * 4 + 3] = (bf16_t)ld.w;
  }
  __syncthreads();
  {
    bf16x4 w;
    w[0] = tile[tx4 * 4 + 0][ty];
    w[1] = tile[tx4 * 4 + 1][ty];
    w[2] = tile[tx4 * 4 + 2][ty];
    w[3] = tile[tx4 * 4 + 3][ty];
    *(bf16x4*)&out[(size_t)(c0 + ty) * R + r0 + tx4 * 4] = w;
  }
}

// ---------------------------------------------------------------------------
// C[M,N] = A[M,K] @ Bt[N,K]^T + bias[N]. bf16 in; OUT_F32 selects store type.
// BM=BN=128, BK=64, 4 waves 2x2. global_load_lds staging with per-lane
// pre-swizzled SOURCE (chunk cs = cl ^ rl), linear LDS dest; ds_read at
// chunk (h*4+quad)^(row&7) -> 2-way bank aliasing (free). 16 K-iters. (R18)
// ---------------------------------------------------------------------------
template <bool OUT_F32>
__global__ __launch_bounds__(256, 3) void gemm_bt_kernel(
    const bf16_t* __restrict__ A, const bf16_t* __restrict__ Bt,
    const float* __restrict__ bias, void* __restrict__ Cv, int M, int N,
    int K) {
  __shared__ __align__(16) bf16_t sA[128 * 64];  // 16 KB
  __shared__ __align__(16) bf16_t sB[128 * 64];  // 16 KB
  const int tid = threadIdx.x;
  const int wave = tid >> 6, lane = tid & 63;
  const int quad = lane >> 4, l16 = lane & 15;
  const int wm = (wave >> 1) * 64, wn = (wave & 1) * 64;
  const int bm = blockIdx.y * 128, bn = blockIdx.x * 128;

  const int rl = lane >> 3, cl = lane & 7;
  const int srow = wave * 32;
  const bf16_t* gA =
      A + (size_t)(bm + srow + rl) * K + (size_t)((cl ^ rl) << 3);
  const bf16_t* gB =
      Bt + (size_t)(bn + srow + rl) * K + (size_t)((cl ^ rl) << 3);
  bf16_t* lA = sA + srow * 64;
  bf16_t* lB = sB + srow * 64;

  f32x4 acc[4][4] = {};

  for (int k0 = 0; k0 < K; k0 += 64) {
    __syncthreads();
#pragma unroll
    for (int c = 0; c < 4; c++) {
      async_copy16(gA + (size_t)(c * 8) * K + k0, lA + c * 512);
      async_copy16(gB + (size_t)(c * 8) * K + k0, lB + c * 512);
    }
    __syncthreads();

#pragma unroll
    for (int h = 0; h < 2; h++) {
      bf16x8 af[4], bfr[4];
#pragma unroll
      for (int i = 0; i < 4; i++) {
        const int row = wm + i * 16 + l16;
        af[i] = *(const bf16x8*)&sA[row * 64 +
                                    (((h * 4 + quad) ^ (row & 7)) << 3)];
      }
#pragma unroll
      for (int j = 0; j < 4; j++) {
        const int row = wn + j * 16 + l16;
        bfr[j] = *(const bf16x8*)&sB[row * 64 +
                                     (((h * 4 + quad) ^ (row & 7)) << 3)];
      }
#pragma unroll
      for (int i = 0; i < 4; i++)
#pragma unroll
        for (int j = 0; j < 4; j++)
          acc[i][j] = __builtin_amdgcn_mfma_f32_16x16x32_bf16(
              af[i], bfr[j], acc[i][j], 0, 0, 0);
    }
  }

#pragma unroll
  for (int j = 0; j < 4; j++) {
    const int col = bn + wn + j * 16 + l16;
    const float bv = bias[col];
#pragma unroll
    for (int i = 0; i < 4; i++) {
#pragma unroll
      for (int r = 0; r < 4; r++) {
        const int row = bm + wm + i * 16 + quad * 4 + r;
        const float v = acc[i][j][r] + bv;
        if (OUT_F32)
          ((float*)Cv)[(size_t)row * N + col] = v;
        else
          ((bf16_t*)Cv)[(size_t)row * N + col] = (bf16_t)v;
      }
    }
  }
}

// ---------------------------------------------------------------------------
// gemm2: BM=64, BN=128, BK=64 (f32 out), R18 swizzle scheme. Grid
// (N/128, M/64) = 512 blocks = 2 blocks/CU. sA 8KB + sB 16KB = 24KB. (R19)
// ---------------------------------------------------------------------------
__global__ __launch_bounds__(256) void gemm_bt64_kernel(
    const bf16_t* __restrict__ A, const bf16_t* __restrict__ Bt,
    const float* __restrict__ bias, float* __restrict__ C, int M, int N,
    int K) {
  __shared__ __align__(16) bf16_t sA[64 * 64];   // 8 KB
  __shared__ __align__(16) bf16_t sB[128 * 64];  // 16 KB
  const int tid = threadIdx.x;
  const int wave = tid >> 6, lane = tid & 63;
  const int quad = lane >> 4, l16 = lane & 15;
  const int wm = (wave >> 1) * 32, wn = (wave & 1) * 64;
  const int bm = blockIdx.y * 64, bn = blockIdx.x * 128;

  const int rl = lane >> 3, cl = lane & 7;
  const bf16_t* gA =
      A + (size_t)(bm + wave * 16 + rl) * K + (size_t)((cl ^ rl) << 3);
  bf16_t* lA = sA + (wave * 16) * 64;
  const bf16_t* gB =
      Bt + (size_t)(bn + wave * 32 + rl) * K + (size_t)((cl ^ rl) << 3);
  bf16_t* lB = sB + (wave * 32) * 64;

  f32x4 acc[2][4] = {};

  for (int k0 = 0; k0 < K; k0 += 64) {
    __syncthreads();
#pragma unroll
    for (int c = 0; c < 2; c++)
      async_copy16(gA + (size_t)(c * 8) * K + k0, lA + c * 512);
#pragma unroll
    for (int c = 0; c < 4; c++)
      async_copy16(gB + (size_t)(c * 8) * K + k0, lB + c * 512);
    __syncthreads();

#pragma unroll
    for (int h = 0; h < 2; h++) {
      bf16x8 af[2], bfr[4];
#pragma unroll
      for (int i = 0; i < 2; i++) {
        const int row = wm + i * 16 + l16;
        af[i] = *(const bf16x8*)&sA[row * 64 +
                                    (((h * 4 + quad) ^ (row & 7)) << 3)];
      }
#pragma unroll
      for (int j = 0; j < 4; j++) {
        const int row = wn + j * 16 + l16;
        bfr[j] = *(const bf16x8*)&sB[row * 64 +
                                     (((h * 4 + quad) ^ (row & 7)) << 3)];
      }
#pragma unroll
      for (int i = 0; i < 2; i++)
#pragma unroll
        for (int j = 0; j < 4; j++)
          acc[i][j] = __builtin_amdgcn_mfma_f32_16x16x32_bf16(
              af[i], bfr[j], acc[i][j], 0, 0, 0);
    }
  }

#pragma unroll
  for (int j = 0; j < 4; j++) {
    const int col = bn + wn + j * 16 + l16;
    const float bv = bias[col];
#pragma unroll
    for (int i = 0; i < 2; i++) {
#pragma unroll
      for (int r = 0; r < 4; r++) {
        const int row = bm + wm + i * 16 + quad * 4 + r;
        C[(size_t)row * N + col] = acc[i][j][r] + bv;
      }
    }
  }
}

// ---------------------------------------------------------------------------
// R23 attention: 8 waves (512 threads), j-split. Wave (wq=w>>1, jh=w&1):
// q-rows q0+wq*16.., j-subtiles {2jh, 2jh+1}. Staging role-split: tid<256
// stages K (R14 index math verbatim), tid>=256 stages V (verbatim).
// Double-buffered sK/sVt, ONE barrier per 64-key tile, hoisted diag.
// End: wave-pair (o,l) merge via LDS (sK reused as 16KB f32 scratch).
// sK : (t,d) at t*64 + (((d>>3) ^ (t&7))<<3) + (d&7)        [8 KB/buf]
// sVt: (d,t) at d*64 + (((t>>2) ^ (d&15))<<2) + (t&3)       [8 KB/buf]
// Balance: X remapped so each CU's 4 resident blocks have sum(X)==62.
// ---------------------------------------------------------------------------
__global__ __launch_bounds__(512, 8) void attn_kernel(
    const bf16_t* __restrict__ qkv, bf16_t* __restrict__ Y) {
  constexpr int T = 2048, C3 = 3072;
  constexpr float CSC = 0.18033688f;  // 0.125 * log2(e)
  constexpr float MB = 20.0f;
  __shared__ __align__(16) bf16_t sK[2][64 * 64];
  __shared__ __align__(16) bf16_t sVt[2][64 * 64];

  const int tid = threadIdx.x;
  const int wave = tid >> 6, lane = tid & 63;
  const int quad = lane >> 4, l16 = lane & 15;
  const int wq = wave >> 1;  // q-row group (16 rows each)
  const int jh = wave & 1;   // handles j = 2*jh, 2*jh+1
  const int bh = blockIdx.y;
  // causal-depth balance remap (bijective in bx for each bh):
  const int flip = (bh >> 3) & 1;
  const int vv = ((int)blockIdx.x + ((bh >> 4) & 1) * 8) & 31;
  const int X = flip ? (31 - vv) : vv;
  const int q0 = X * 64;
  const int b = bh >> 4, h = bh & 15;
  const size_t base = (size_t)b * T * C3 + (size_t)h * 64;

  // Q as B-operand: lane n=l16=query, k = quad*8+j (pair waves share rows)
  const int qrow = q0 + wq * 16 + l16;
  const bf16x8 qf0 = *(const bf16x8*)&qkv[base + (size_t)qrow * C3 + quad * 8];
  const bf16x8 qf1 =
      *(const bf16x8*)&qkv[base + (size_t)qrow * C3 + 32 + quad * 8];

  f32x4 o[4] = {};   // partial O over this wave's key subset
  f32x4 l4 = {0.f, 0.f, 0.f, 0.f};

  // staging roles: tid<256 stages K; tid>=256 stages V (verbatim R14 math).
  const bool krole = tid < 256;
  const int st = (tid & 255) >> 2, sseg = tid & 3;  // K: key row, 32B seg
  const bf16_t* gK = &qkv[base + (size_t)st * C3 + 1024 + sseg * 16];
  const int kq = (tid & 255) >> 4, dq = tid & 15;   // V: key-quad, d-quad
  const bf16_t* gV = &qkv[base + (size_t)(4 * kq) * C3 + 2048 + dq * 4];

  bf16x8 kr0 = {}, kr1 = {};
  bf16x4 vA0 = {}, vA1 = {}, vA2 = {}, vA3 = {};
  if (krole) {
    kr0 = *(const bf16x8*)gK;
    kr1 = *(const bf16x8*)(gK + 8);
  } else {
    vA0 = *(const bf16x4*)gV;
    vA1 = *(const bf16x4*)(gV + C3);
    vA2 = *(const bf16x4*)(gV + 2 * C3);
    vA3 = *(const bf16x4*)(gV + 3 * C3);
  }

  // ---- main loop: tiles 0..X-1 (branch-free compute) ----
  for (int kt = 0; kt < X; kt++) {
    const int p = kt & 1;
    if (krole) {
      *(bf16x8*)&sK[p][st * 64 + (((2 * sseg + 0) ^ (st & 7)) << 3)] = kr0;
      *(bf16x8*)&sK[p][st * 64 + (((2 * sseg + 1) ^ (st & 7)) << 3)] = kr1;
    } else {
#pragma unroll
      for (int i = 0; i < 4; i++) {
        const int d = dq * 4 + i;
        bf16x4 w;
        w[0] = vA0[i]; w[1] = vA1[i]; w[2] = vA2[i]; w[3] = vA3[i];
        *(bf16x4*)&sVt[p][d * 64 + ((kq ^ (d & 15)) << 2)] = w;
      }
    }
    // prefetch next tile (kt+1 <= X always valid)
    {
      const size_t off = (size_t)(kt + 1) * 64 * C3;
      if (krole) {
        kr0 = *(const bf16x8*)(gK + off);
        kr1 = *(const bf16x8*)(gK + off + 8);
      } else {
        vA0 = *(const bf16x4*)(gV + off);
        vA1 = *(const bf16x4*)(gV + off + C3);
        vA2 = *(const bf16x4*)(gV + off + 2 * C3);
        vA3 = *(const bf16x4*)(gV + off + 3 * C3);
      }
    }
    __syncthreads();  // single barrier: buf p visible; buf 1-p free

#pragma unroll
    for (int jj = 0; jj < 2; jj++) {
      const int j = jh * 2 + jj;
      const int trow = j * 16 + l16;
      bf16x8 kf0 =
          *(const bf16x8*)&sK[p][trow * 64 + ((quad ^ (trow & 7)) << 3)];
      bf16x8 kf1 =
          *(const bf16x8*)&sK[p][trow * 64 + (((4 + quad) ^ (trow & 7)) << 3)];
      f32x4 s2 = {};
      __builtin_amdgcn_s_setprio(1);
      s2 = __builtin_amdgcn_mfma_f32_16x16x32_bf16(kf0, qf0, s2, 0, 0, 0);
      s2 = __builtin_amdgcn_mfma_f32_16x16x32_bf16(kf1, qf1, s2, 0, 0, 0);
      __builtin_amdgcn_s_setprio(0);
#pragma unroll
      for (int r = 0; r < 4; r++) s2[r] = EXP2F(fmaf(s2[r], CSC, -MB));
      l4 += s2;
      bf16x4 pb;
      pb[0] = (bf16_t)s2[0]; pb[1] = (bf16_t)s2[1];
      pb[2] = (bf16_t)s2[2]; pb[3] = (bf16_t)s2[3];
      union { bf16x4 bv; short4v sv; } u;
      u.bv = pb;
      const short4v pa = u.sv;
      __builtin_amdgcn_s_setprio(1);
#pragma unroll
      for (int n16 = 0; n16 < 4; n16++) {
        const int d = n16 * 16 + l16;
        const short4v vf = *(const short4v*)&sVt[p][d * 64 +
                                                    (((j * 4 + quad) ^ (d & 15))
                                                     << 2)];
        o[n16] =
            __builtin_amdgcn_mfma_f32_16x16x16bf16_1k(pa, vf, o[n16], 0, 0, 0);
      }
      __builtin_amdgcn_s_setprio(0);
    }
  }

  // ---- diagonal tile kt == X (hoisted; j-skip + diag mask) ----
  {
    const int p = X & 1;
    if (krole) {
      *(bf16x8*)&sK[p][st * 64 + (((2 * sseg + 0) ^ (st & 7)) << 3)] = kr0;
      *(bf16x8*)&sK[p][st * 64 + (((2 * sseg + 1) ^ (st & 7)) << 3)] = kr1;
    } else {
#pragma unroll
      for (int i = 0; i < 4; i++) {
        const int d = dq * 4 + i;
        bf16x4 w;
        w[0] = vA0[i]; w[1] = vA1[i]; w[2] = vA2[i]; w[3] = vA3[i];
        *(bf16x4*)&sVt[p][d * 64 + ((kq ^ (d & 15)) << 2)] = w;
      }
    }
    __syncthreads();

#pragma unroll
    for (int jj = 0; jj < 2; jj++) {
      const int j = jh * 2 + jj;
      if (j > wq) continue;  // wave-uniform; P would be all-zero
      const int trow = j * 16 + l16;
      bf16x8 kf0 =
          *(const bf16x8*)&sK[p][trow * 64 + ((quad ^ (trow & 7)) << 3)];
      bf16x8 kf1 =
          *(const bf16x8*)&sK[p][trow * 64 + (((4 + quad) ^ (trow & 7)) << 3)];
      f32x4 s2 = {};
      __builtin_amdgcn_s_setprio(1);
      s2 = __builtin_amdgcn_mfma_f32_16x16x32_bf16(kf0, qf0, s2, 0, 0, 0);
      s2 = __builtin_amdgcn_mfma_f32_16x16x32_bf16(kf1, qf1, s2, 0, 0, 0);
      __builtin_amdgcn_s_setprio(0);
      const bool diag = (j == wq);
#pragma unroll
      for (int r = 0; r < 4; r++) {
        float pv = EXP2F(fmaf(s2[r], CSC, -MB));
        if (diag && (quad * 4 + r > l16)) pv = 0.f;
        s2[r] = pv;
      }
      l4 += s2;
      bf16x4 pb;
      pb[0] = (bf16_t)s2[0]; pb[1] = (bf16_t)s2[1];
      pb[2] = (bf16_t)s2[2]; pb[3] = (bf16_t)s2[3];
      union { bf16x4 bv; short4v sv; } u;
      u.bv = pb;
      const short4v pa = u.sv;
      __builtin_amdgcn_s_setprio(1);
#pragma unroll
      for (int n16 = 0; n16 < 4; n16++) {
        const int d = n16 * 16 + l16;
        const short4v vf = *(const short4v*)&sVt[p][d * 64 +
                                                    (((j * 4 + quad) ^ (d & 15))
                                                     << 2)];
        o[n16] =
            __builtin_amdgcn_mfma_f32_16x16x16bf16_1k(pa, vf, o[n16], 0, 0, 0);
      }
      __builtin_amdgcn_s_setprio(0);
    }
  }

  // ---- epilogue: reduce l over quads, merge wave pair via LDS, store ----
  float l_acc = (l4[0] + l4[1]) + (l4[2] + l4[3]);
  l_acc += __shfl_xor(l_acc, 16);
  l_acc += __shfl_xor(l_acc, 32);
  // l_acc now: total l for query l16 over THIS wave's key subset.

  __syncthreads();  // all compute done; sK/sVt reusable as merge scratch
  float* mo = (float*)&sK[0][0];   // [wq][lane][16] f32 = 16 KB (== sK)
  float* ml = (float*)&sVt[0][0];  // [wq][16] f32
  if (jh == 1) {
    float* dst = mo + ((size_t)(wq * 64 + lane)) * 16;
#pragma unroll
    for (int n16 = 0; n16 < 4; n16++) *(f32x4*)(dst + n16 * 4) = o[n16];
    if (quad == 0) ml[wq * 16 + l16] = l_acc;
  }
  __syncthreads();
  if (jh == 0) {
    const float* src = mo + ((size_t)(wq * 64 + lane)) * 16;
#pragma unroll
    for (int n16 = 0; n16 < 4; n16++) o[n16] += *(const f32x4*)(src + n16 * 4);
    const float lsum = l_acc + ml[wq * 16 + l16];
#pragma unroll
    for (int r = 0; r < 4; r++) {
      const float lr = __shfl(lsum, quad * 4 + r);
      const float inv = 1.0f / lr;
      const int row = q0 + wq * 16 + quad * 4 + r;
#pragma unroll
      for (int n16 = 0; n16 < 4; n16++)
        Y[((size_t)b * T + row) * 1024 + h * 64 + n16 * 16 + l16] =
            (bf16_t)(o[n16][r] * inv);
    }
  }
}

// ---------------------------------------------------------------------------
extern "C" void kernel_launch(void* const* d_in, const int* in_sizes, int n_in,
                              void* d_out, int out_size, void* d_ws,
                              size_t ws_size, hipStream_t stream) {
  const float* x = nullptr;
  const float* w_qkv = nullptr;
  const float* b_qkv = nullptr;
  const float* w_out = nullptr;
  const float* b_out = nullptr;
  for (int i = 0; i < n_in; i++) {
    switch (in_sizes[i]) {
      case 4194304: x = (const float*)d_in[i]; break;
      case 3145728: w_qkv = (const float*)d_in[i]; break;
      case 3072:    b_qkv = (const float*)d_in[i]; break;
      case 1048576: w_out = (const float*)d_in[i]; break;
      case 1024:    b_out = (const float*)d_in[i]; break;
      default: break;
    }
  }
  float* out = (float*)d_out;  // FP32 output

  bf16_t* xb = (bf16_t*)d_ws;
  bf16_t* wqkvT = xb + (size_t)4194304;
  bf16_t* woutT = wqkvT + (size_t)3145728;
  bf16_t* qkv = woutT + (size_t)1048576;
  bf16_t* Y = qkv + (size_t)12582912;

  prep_kernel<<<6144, 256, 0, stream>>>(x, w_qkv, w_out, xb, wqkvT, woutT);
  gemm_bt_kernel<false><<<dim3(24, 32), 256, 0, stream>>>(
      xb, wqkvT, b_qkv, (void*)qkv, 4096, 3072, 1024);
  attn_kernel<<<dim3(32, 32), 512, 0, stream>>>(qkv, Y);  // UNCONDITIONAL 512
  gemm_bt64_kernel<<<dim3(8, 64), 256, 0, stream>>>(
      Y, woutT, b_out, out, 4096, 1024, 1024);
}

// Round 13
// 195.973 us; speedup vs baseline: 1.1356x; 1.1356x over previous
//
#include <hip/hip_runtime.h>
#include <hip/hip_bf16.h>
#include <stdint.h>

// SelfAttention B=2,T=2048,C=1024,H=16,hd=64. Inputs fp32, output fp32.
// R24: R23's 8-wave j-split attn is CORRECT (passed) but launch_bounds
// (512,8) forced a 32-VGPR cap -> accumulator SPILL (WRITE_SIZE 8->108MB,
// FETCH 62->96MB, MfmaUtil 10%, attn 98us). Fix: __launch_bounds__(512,4)
// -> 128-VGPR budget, zero spill, 2 blocks x 8 waves = 16 waves/CU (same
// as R14) but with role-split staging + halved per-wave j-chain (the two
// waves of a q-row pair interleave their QK->exp->PV chains on the SIMD).
// Everything else byte-identical to R23. gemm1=R18, gemm2=R19, prep=R21.

typedef __bf16 bf16_t;
typedef __attribute__((ext_vector_type(8))) __bf16 bf16x8;
typedef __attribute__((ext_vector_type(4))) __bf16 bf16x4;
typedef __attribute__((ext_vector_type(4))) short short4v;
typedef __attribute__((ext_vector_type(4))) float f32x4;

static_assert(sizeof(bf16x8) == 16, "bf16x8 must be 16B");

// EXP2F: device-only usage; host-pass fallback value is never executed.
#if defined(__has_builtin)
#if __has_builtin(__builtin_amdgcn_exp2f)
#define EXP2F(x) __builtin_amdgcn_exp2f(x)
#endif
#endif
#ifndef EXP2F
#define EXP2F(x) exp2f(x)
#endif

// async global->LDS, 16B/lane. LDS dest = wave-uniform base + lane*16.
__device__ inline void async_copy16(const bf16_t* gsrc, bf16_t* lds_dst) {
  __builtin_amdgcn_global_load_lds(
      (const __attribute__((address_space(1))) uint32_t*)(const void*)gsrc,
      (__attribute__((address_space(3))) uint32_t*)(void*)lds_dst,
      16, 0, 0);
}

// ---------------------------------------------------------------------------
// Merged prep: blocks [0,2048) convx; [2048,5120) transpose w_qkv;
// [5120,6144) transpose w_out. Transpose: float4 read, bf16x4 write. (R21)
// ---------------------------------------------------------------------------
__global__ __launch_bounds__(256) void prep_kernel(
    const float* __restrict__ x, const float* __restrict__ wq,
    const float* __restrict__ wo, bf16_t* __restrict__ xb,
    bf16_t* __restrict__ wqkvT, bf16_t* __restrict__ woutT) {
  __shared__ bf16_t tile[32][33];
  const int bid = blockIdx.x;
  if (bid < 2048) {
    const int i = bid * 256 + threadIdx.x;  // < 524288
    const float4* s = (const float4*)x;
    float4 a = s[i * 2], b = s[i * 2 + 1];
    bf16x8 o;
    o[0] = (bf16_t)a.x; o[1] = (bf16_t)a.y; o[2] = (bf16_t)a.z; o[3] = (bf16_t)a.w;
    o[4] = (bf16_t)b.x; o[5] = (bf16_t)b.y; o[6] = (bf16_t)b.z; o[7] = (bf16_t)b.w;
    ((bf16x8*)xb)[i] = o;
    return;
  }
  const bool isq = bid < 5120;
  const int id = isq ? bid - 2048 : bid - 5120;
  const int C = isq ? 3072 : 1024;
  const int R = 1024;
  const int nbx = isq ? 96 : 32;
  const float* in = isq ? wq : wo;
  bf16_t* out = isq ? wqkvT : woutT;
  const int c0 = (id % nbx) * 32, r0 = (id / nbx) * 32;
  const int tx4 = threadIdx.x & 7;   // col group (4 cols each)
  const int ty = threadIdx.x >> 3;   // row [0,32)
  {
    const float4 ld =
        *(const float4*)&in[(size_t)(r0 + ty) * C + c0 + tx4 * 4];
    tile[ty][tx4 * 4 + 0] = (bf16_t)ld.x;
    tile[ty][tx4 * 4 + 1] = (bf16_t)ld.y;
    tile[ty][tx4 * 4 + 2] = (bf16_t)ld.z;
    tile[ty][tx4 * 4 + 3] = (bf16_t)ld.w;
  }
  __syncthreads();
  {
    bf16x4 w;
    w[0] = tile[tx4 * 4 + 0][ty];
    w[1] = tile[tx4 * 4 + 1][ty];
    w[2] = tile[tx4 * 4 + 2][ty];
    w[3] = tile[tx4 * 4 + 3][ty];
    *(bf16x4*)&out[(size_t)(c0 + ty) * R + r0 + tx4 * 4] = w;
  }
}

// ---------------------------------------------------------------------------
// C[M,N] = A[M,K] @ Bt[N,K]^T + bias[N]. bf16 in; OUT_F32 selects store type.
// BM=BN=128, BK=64, 4 waves 2x2. global_load_lds staging with per-lane
// pre-swizzled SOURCE (chunk cs = cl ^ rl), linear LDS dest; ds_read at
// chunk (h*4+quad)^(row&7) -> 2-way bank aliasing (free). 16 K-iters. (R18)
// ---------------------------------------------------------------------------
template <bool OUT_F32>
__global__ __launch_bounds__(256, 3) void gemm_bt_kernel(
    const bf16_t* __restrict__ A, const bf16_t* __restrict__ Bt,
    const float* __restrict__ bias, void* __restrict__ Cv, int M, int N,
    int K) {
  __shared__ __align__(16) bf16_t sA[128 * 64];  // 16 KB
  __shared__ __align__(16) bf16_t sB[128 * 64];  // 16 KB
  const int tid = threadIdx.x;
  const int wave = tid >> 6, lane = tid & 63;
  const int quad = lane >> 4, l16 = lane & 15;
  const int wm = (wave >> 1) * 64, wn = (wave & 1) * 64;
  const int bm = blockIdx.y * 128, bn = blockIdx.x * 128;

  const int rl = lane >> 3, cl = lane & 7;
  const int srow = wave * 32;
  const bf16_t* gA =
      A + (size_t)(bm + srow + rl) * K + (size_t)((cl ^ rl) << 3);
  const bf16_t* gB =
      Bt + (size_t)(bn + srow + rl) * K + (size_t)((cl ^ rl) << 3);
  bf16_t* lA = sA + srow * 64;
  bf16_t* lB = sB + srow * 64;

  f32x4 acc[4][4] = {};

  for (int k0 = 0; k0 < K; k0 += 64) {
    __syncthreads();
#pragma unroll
    for (int c = 0; c < 4; c++) {
      async_copy16(gA + (size_t)(c * 8) * K + k0, lA + c * 512);
      async_copy16(gB + (size_t)(c * 8) * K + k0, lB + c * 512);
    }
    __syncthreads();

#pragma unroll
    for (int h = 0; h < 2; h++) {
      bf16x8 af[4], bfr[4];
#pragma unroll
      for (int i = 0; i < 4; i++) {
        const int row = wm + i * 16 + l16;
        af[i] = *(const bf16x8*)&sA[row * 64 +
                                    (((h * 4 + quad) ^ (row & 7)) << 3)];
      }
#pragma unroll
      for (int j = 0; j < 4; j++) {
        const int row = wn + j * 16 + l16;
        bfr[j] = *(const bf16x8*)&sB[row * 64 +
                                     (((h * 4 + quad) ^ (row & 7)) << 3)];
      }
#pragma unroll
      for (int i = 0; i < 4; i++)
#pragma unroll
        for (int j = 0; j < 4; j++)
          acc[i][j] = __builtin_amdgcn_mfma_f32_16x16x32_bf16(
              af[i], bfr[j], acc[i][j], 0, 0, 0);
    }
  }

#pragma unroll
  for (int j = 0; j < 4; j++) {
    const int col = bn + wn + j * 16 + l16;
    const float bv = bias[col];
#pragma unroll
    for (int i = 0; i < 4; i++) {
#pragma unroll
      for (int r = 0; r < 4; r++) {
        const int row = bm + wm + i * 16 + quad * 4 + r;
        const float v = acc[i][j][r] + bv;
        if (OUT_F32)
          ((float*)Cv)[(size_t)row * N + col] = v;
        else
          ((bf16_t*)Cv)[(size_t)row * N + col] = (bf16_t)v;
      }
    }
  }
}

// ---------------------------------------------------------------------------
// gemm2: BM=64, BN=128, BK=64 (f32 out), R18 swizzle scheme. Grid
// (N/128, M/64) = 512 blocks = 2 blocks/CU. sA 8KB + sB 16KB = 24KB. (R19)
// ---------------------------------------------------------------------------
__global__ __launch_bounds__(256) void gemm_bt64_kernel(
    const bf16_t* __restrict__ A, const bf16_t* __restrict__ Bt,
    const float* __restrict__ bias, float* __restrict__ C, int M, int N,
    int K) {
  __shared__ __align__(16) bf16_t sA[64 * 64];   // 8 KB
  __shared__ __align__(16) bf16_t sB[128 * 64];  // 16 KB
  const int tid = threadIdx.x;
  const int wave = tid >> 6, lane = tid & 63;
  const int quad = lane >> 4, l16 = lane & 15;
  const int wm = (wave >> 1) * 32, wn = (wave & 1) * 64;
  const int bm = blockIdx.y * 64, bn = blockIdx.x * 128;

  const int rl = lane >> 3, cl = lane & 7;
  const bf16_t* gA =
      A + (size_t)(bm + wave * 16 + rl) * K + (size_t)((cl ^ rl) << 3);
  bf16_t* lA = sA + (wave * 16) * 64;
  const bf16_t* gB =
      Bt + (size_t)(bn + wave * 32 + rl) * K + (size_t)((cl ^ rl) << 3);
  bf16_t* lB = sB + (wave * 32) * 64;

  f32x4 acc[2][4] = {};

  for (int k0 = 0; k0 < K; k0 += 64) {
    __syncthreads();
#pragma unroll
    for (int c = 0; c < 2; c++)
      async_copy16(gA + (size_t)(c * 8) * K + k0, lA + c * 512);
#pragma unroll
    for (int c = 0; c < 4; c++)
      async_copy16(gB + (size_t)(c * 8) * K + k0, lB + c * 512);
    __syncthreads();

#pragma unroll
    for (int h = 0; h < 2; h++) {
      bf16x8 af[2], bfr[4];
#pragma unroll
      for (int i = 0; i < 2; i++) {
        const int row = wm + i * 16 + l16;
        af[i] = *(const bf16x8*)&sA[row * 64 +
                                    (((h * 4 + quad) ^ (row & 7)) << 3)];
      }
#pragma unroll
      for (int j = 0; j < 4; j++) {
        const int row = wn + j * 16 + l16;
        bfr[j] = *(const bf16x8*)&sB[row * 64 +
                                     (((h * 4 + quad) ^ (row & 7)) << 3)];
      }
#pragma unroll
      for (int i = 0; i < 2; i++)
#pragma unroll
        for (int j = 0; j < 4; j++)
          acc[i][j] = __builtin_amdgcn_mfma_f32_16x16x32_bf16(
              af[i], bfr[j], acc[i][j], 0, 0, 0);
    }
  }

#pragma unroll
  for (int j = 0; j < 4; j++) {
    const int col = bn + wn + j * 16 + l16;
    const float bv = bias[col];
#pragma unroll
    for (int i = 0; i < 2; i++) {
#pragma unroll
      for (int r = 0; r < 4; r++) {
        const int row = bm + wm + i * 16 + quad * 4 + r;
        C[(size_t)row * N + col] = acc[i][j][r] + bv;
      }
    }
  }
}

// ---------------------------------------------------------------------------
// R24 attention: 8 waves (512 threads), j-split, launch_bounds(512,4) —
// 128-VGPR budget, no spill. Wave (wq=w>>1, jh=w&1): q-rows q0+wq*16..,
// j-subtiles {2jh, 2jh+1}. Staging role-split: tid<256 stages K (R14
// index math verbatim), tid>=256 stages V (verbatim). Double-buffered
// sK/sVt, ONE barrier per 64-key tile, hoisted diag. End: wave-pair (o,l)
// merge via LDS (sK reused as 16KB f32 scratch).
// sK : (t,d) at t*64 + (((d>>3) ^ (t&7))<<3) + (d&7)        [8 KB/buf]
// sVt: (d,t) at d*64 + (((t>>2) ^ (d&15))<<2) + (t&3)       [8 KB/buf]
// Balance: X remapped so each CU's resident blocks have balanced sum(X).
// ---------------------------------------------------------------------------
__global__ __launch_bounds__(512, 4) void attn_kernel(
    const bf16_t* __restrict__ qkv, bf16_t* __restrict__ Y) {
  constexpr int T = 2048, C3 = 3072;
  constexpr float CSC = 0.18033688f;  // 0.125 * log2(e)
  constexpr float MB = 20.0f;
  __shared__ __align__(16) bf16_t sK[2][64 * 64];
  __shared__ __align__(16) bf16_t sVt[2][64 * 64];

  const int tid = threadIdx.x;
  const int wave = tid >> 6, lane = tid & 63;
  const int quad = lane >> 4, l16 = lane & 15;
  const int wq = wave >> 1;  // q-row group (16 rows each)
  const int jh = wave & 1;   // handles j = 2*jh, 2*jh+1
  const int bh = blockIdx.y;
  // causal-depth balance remap (bijective in bx for each bh):
  const int flip = (bh >> 3) & 1;
  const int vv = ((int)blockIdx.x + ((bh >> 4) & 1) * 8) & 31;
  const int X = flip ? (31 - vv) : vv;
  const int q0 = X * 64;
  const int b = bh >> 4, h = bh & 15;
  const size_t base = (size_t)b * T * C3 + (size_t)h * 64;

  // Q as B-operand: lane n=l16=query, k = quad*8+j (pair waves share rows)
  const int qrow = q0 + wq * 16 + l16;
  const bf16x8 qf0 = *(const bf16x8*)&qkv[base + (size_t)qrow * C3 + quad * 8];
  const bf16x8 qf1 =
      *(const bf16x8*)&qkv[base + (size_t)qrow * C3 + 32 + quad * 8];

  f32x4 o[4] = {};   // partial O over this wave's key subset
  f32x4 l4 = {0.f, 0.f, 0.f, 0.f};

  // staging roles: tid<256 stages K; tid>=256 stages V (verbatim R14 math).
  const bool krole = tid < 256;
  const int st = (tid & 255) >> 2, sseg = tid & 3;  // K: key row, 32B seg
  const bf16_t* gK = &qkv[base + (size_t)st * C3 + 1024 + sseg * 16];
  const int kq = (tid & 255) >> 4, dq = tid & 15;   // V: key-quad, d-quad
  const bf16_t* gV = &qkv[base + (size_t)(4 * kq) * C3 + 2048 + dq * 4];

  bf16x8 kr0 = {}, kr1 = {};
  bf16x4 vA0 = {}, vA1 = {}, vA2 = {}, vA3 = {};
  if (krole) {
    kr0 = *(const bf16x8*)gK;
    kr1 = *(const bf16x8*)(gK + 8);
  } else {
    vA0 = *(const bf16x4*)gV;
    vA1 = *(const bf16x4*)(gV + C3);
    vA2 = *(const bf16x4*)(gV + 2 * C3);
    vA3 = *(const bf16x4*)(gV + 3 * C3);
  }

  // ---- main loop: tiles 0..X-1 (branch-free compute) ----
  for (int kt = 0; kt < X; kt++) {
    const int p = kt & 1;
    if (krole) {
      *(bf16x8*)&sK[p][st * 64 + (((2 * sseg + 0) ^ (st & 7)) << 3)] = kr0;
      *(bf16x8*)&sK[p][st * 64 + (((2 * sseg + 1) ^ (st & 7)) << 3)] = kr1;
    } else {
#pragma unroll
      for (int i = 0; i < 4; i++) {
        const int d = dq * 4 + i;
        bf16x4 w;
        w[0] = vA0[i]; w[1] = vA1[i]; w[2] = vA2[i]; w[3] = vA3[i];
        *(bf16x4*)&sVt[p][d * 64 + ((kq ^ (d & 15)) << 2)] = w;
      }
    }
    // prefetch next tile (kt+1 <= X always valid)
    {
      const size_t off = (size_t)(kt + 1) * 64 * C3;
      if (krole) {
        kr0 = *(const bf16x8*)(gK + off);
        kr1 = *(const bf16x8*)(gK + off + 8);
      } else {
        vA0 = *(const bf16x4*)(gV + off);
        vA1 = *(const bf16x4*)(gV + off + C3);
        vA2 = *(const bf16x4*)(gV + off + 2 * C3);
        vA3 = *(const bf16x4*)(gV + off + 3 * C3);
      }
    }
    __syncthreads();  // single barrier: buf p visible; buf 1-p free

#pragma unroll
    for (int jj = 0; jj < 2; jj++) {
      const int j = jh * 2 + jj;
      const int trow = j * 16 + l16;
      bf16x8 kf0 =
          *(const bf16x8*)&sK[p][trow * 64 + ((quad ^ (trow & 7)) << 3)];
      bf16x8 kf1 =
          *(const bf16x8*)&sK[p][trow * 64 + (((4 + quad) ^ (trow & 7)) << 3)];
      f32x4 s2 = {};
      __builtin_amdgcn_s_setprio(1);
      s2 = __builtin_amdgcn_mfma_f32_16x16x32_bf16(kf0, qf0, s2, 0, 0, 0);
      s2 = __builtin_amdgcn_mfma_f32_16x16x32_bf16(kf1, qf1, s2, 0, 0, 0);
      __builtin_amdgcn_s_setprio(0);
#pragma unroll
      for (int r = 0; r < 4; r++) s2[r] = EXP2F(fmaf(s2[r], CSC, -MB));
      l4 += s2;
      bf16x4 pb;
      pb[0] = (bf16_t)s2[0]; pb[1] = (bf16_t)s2[1];
      pb[2] = (bf16_t)s2[2]; pb[3] = (bf16_t)s2[3];
      union { bf16x4 bv; short4v sv; } u;
      u.bv = pb;
      const short4v pa = u.sv;
      __builtin_amdgcn_s_setprio(1);
#pragma unroll
      for (int n16 = 0; n16 < 4; n16++) {
        const int d = n16 * 16 + l16;
        const short4v vf = *(const short4v*)&sVt[p][d * 64 +
                                                    (((j * 4 + quad) ^ (d & 15))
                                                     << 2)];
        o[n16] =
            __builtin_amdgcn_mfma_f32_16x16x16bf16_1k(pa, vf, o[n16], 0, 0, 0);
      }
      __builtin_amdgcn_s_setprio(0);
    }
  }

  // ---- diagonal tile kt == X (hoisted; j-skip + diag mask) ----
  {
    const int p = X & 1;
    if (krole) {
      *(bf16x8*)&sK[p][st * 64 + (((2 * sseg + 0) ^ (st & 7)) << 3)] = kr0;
      *(bf16x8*)&sK[p][st * 64 + (((2 * sseg + 1) ^ (st & 7)) << 3)] = kr1;
    } else {
#pragma unroll
      for (int i = 0; i < 4; i++) {
        const int d = dq * 4 + i;
        bf16x4 w;
        w[0] = vA0[i]; w[1] = vA1[i]; w[2] = vA2[i]; w[3] = vA3[i];
        *(bf16x4*)&sVt[p][d * 64 + ((kq ^ (d & 15)) << 2)] = w;
      }
    }
    __syncthreads();

#pragma unroll
    for (int jj = 0; jj < 2; jj++) {
      const int j = jh * 2 + jj;
      if (j > wq) continue;  // wave-uniform; P would be all-zero
      const int trow = j * 16 + l16;
      bf16x8 kf0 =
          *(const bf16x8*)&sK[p][trow * 64 + ((quad ^ (trow & 7)) << 3)];
      bf16x8 kf1 =
          *(const bf16x8*)&sK[p][trow * 64 + (((4 + quad) ^ (trow & 7)) << 3)];
      f32x4 s2 = {};
      __builtin_amdgcn_s_setprio(1);
      s2 = __builtin_amdgcn_mfma_f32_16x16x32_bf16(kf0, qf0, s2, 0, 0, 0);
      s2 = __builtin_amdgcn_mfma_f32_16x16x32_bf16(kf1, qf1, s2, 0, 0, 0);
      __builtin_amdgcn_s_setprio(0);
      const bool diag = (j == wq);
#pragma unroll
      for (int r = 0; r < 4; r++) {
        float pv = EXP2F(fmaf(s2[r], CSC, -MB));
        if (diag && (quad * 4 + r > l16)) pv = 0.f;
        s2[r] = pv;
      }
      l4 += s2;
      bf16x4 pb;
      pb[0] = (bf16_t)s2[0]; pb[1] = (bf16_t)s2[1];
      pb[2] = (bf16_t)s2[2]; pb[3] = (bf16_t)s2[3];
      union { bf16x4 bv; short4v sv; } u;
      u.bv = pb;
      const short4v pa = u.sv;
      __builtin_amdgcn_s_setprio(1);
#pragma unroll
      for (int n16 = 0; n16 < 4; n16++) {
        const int d = n16 * 16 + l16;
        const short4v vf = *(const short4v*)&sVt[p][d * 64 +
                                                    (((j * 4 + quad) ^ (d & 15))
                                                     << 2)];
        o[n16] =
            __builtin_amdgcn_mfma_f32_16x16x16bf16_1k(pa, vf, o[n16], 0, 0, 0);
      }
      __builtin_amdgcn_s_setprio(0);
    }
  }

  // ---- epilogue: reduce l over quads, merge wave pair via LDS, store ----
  float l_acc = (l4[0] + l4[1]) + (l4[2] + l4[3]);
  l_acc += __shfl_xor(l_acc, 16);
  l_acc += __shfl_xor(l_acc, 32);
  // l_acc now: total l for query l16 over THIS wave's key subset.

  __syncthreads();  // all compute done; sK/sVt reusable as merge scratch
  float* mo = (float*)&sK[0][0];   // [wq][lane][16] f32 = 16 KB (== sK)
  float* ml = (float*)&sVt[0][0];  // [wq][16] f32
  if (jh == 1) {
    float* dst = mo + ((size_t)(wq * 64 + lane)) * 16;
#pragma unroll
    for (int n16 = 0; n16 < 4; n16++) *(f32x4*)(dst + n16 * 4) = o[n16];
    if (quad == 0) ml[wq * 16 + l16] = l_acc;
  }
  __syncthreads();
  if (jh == 0) {
    const float* src = mo + ((size_t)(wq * 64 + lane)) * 16;
#pragma unroll
    for (int n16 = 0; n16 < 4; n16++) o[n16] += *(const f32x4*)(src + n16 * 4);
    const float lsum = l_acc + ml[wq * 16 + l16];
#pragma unroll
    for (int r = 0; r < 4; r++) {
      const float lr = __shfl(lsum, quad * 4 + r);
      const float inv = 1.0f / lr;
      const int row = q0 + wq * 16 + quad * 4 + r;
#pragma unroll
      for (int n16 = 0; n16 < 4; n16++)
        Y[((size_t)b * T + row) * 1024 + h * 64 + n16 * 16 + l16] =
            (bf16_t)(o[n16][r] * inv);
    }
  }
}

// ---------------------------------------------------------------------------
extern "C" void kernel_launch(void* const* d_in, const int* in_sizes, int n_in,
                              void* d_out, int out_size, void* d_ws,
                              size_t ws_size, hipStream_t stream) {
  const float* x = nullptr;
  const float* w_qkv = nullptr;
  const float* b_qkv = nullptr;
  const float* w_out = nullptr;
  const float* b_out = nullptr;
  for (int i = 0; i < n_in; i++) {
    switch (in_sizes[i]) {
      case 4194304: x = (const float*)d_in[i]; break;
      case 3145728: w_qkv = (const float*)d_in[i]; break;
      case 3072:    b_qkv = (const float*)d_in[i]; break;
      case 1048576: w_out = (const float*)d_in[i]; break;
      case 1024:    b_out = (const float*)d_in[i]; break;
      default: break;
    }
  }
  float* out = (float*)d_out;  // FP32 output

  bf16_t* xb = (bf16_t*)d_ws;
  bf16_t* wqkvT = xb + (size_t)4194304;
  bf16_t* woutT = wqkvT + (size_t)3145728;
  bf16_t* qkv = woutT + (size_t)1048576;
  bf16_t* Y = qkv + (size_t)12582912;

  prep_kernel<<<6144, 256, 0, stream>>>(x, w_qkv, w_out, xb, wqkvT, woutT);
  gemm_bt_kernel<false><<<dim3(24, 32), 256, 0, stream>>>(
      xb, wqkvT, b_qkv, (void*)qkv, 4096, 3072, 1024);
  attn_kernel<<<dim3(32, 32), 512, 0, stream>>>(qkv, Y);
  gemm_bt64_kernel<<<dim3(8, 64), 256, 0, stream>>>(
      Y, woutT, b_out, out, 4096, 1024, 1024);
}

// Round 14
// 173.101 us; speedup vs baseline: 1.2856x; 1.1321x over previous
//
#include <hip/hip_runtime.h>
#include <hip/hip_bf16.h>
#include <stdint.h>

// SelfAttention B=2,T=2048,C=1024,H=16,hd=64. Inputs fp32, output fp32.
// R25: REVERT to R22 (session best, 171.3us). R24's j-split passed but
// regressed (72.8 vs 48.9us): halving per-wave work per barrier interval
// doubles relative barrier/staging overhead, and 2 lockstep 8-wave groups
// per CU < 4 independent 4-wave groups for latency hiding. At (512,8) it
// spills (R23); at (512,4) it underperforms (R24) -> design space closed.
// Config: attn = R14 walk + gload_lds K-staging (R22), gemm1 = R18
// (BK=64 + src-swizzled gload_lds), gemm2 = R19 (same scheme), prep = R21
// (vectorized transpose). All components individually proven.

typedef __bf16 bf16_t;
typedef __attribute__((ext_vector_type(8))) __bf16 bf16x8;
typedef __attribute__((ext_vector_type(4))) __bf16 bf16x4;
typedef __attribute__((ext_vector_type(4))) short short4v;
typedef __attribute__((ext_vector_type(4))) float f32x4;

static_assert(sizeof(bf16x8) == 16, "bf16x8 must be 16B");

// EXP2F: device-only usage; host-pass fallback value is never executed.
#if defined(__has_builtin)
#if __has_builtin(__builtin_amdgcn_exp2f)
#define EXP2F(x) __builtin_amdgcn_exp2f(x)
#endif
#endif
#ifndef EXP2F
#define EXP2F(x) exp2f(x)
#endif

// async global->LDS, 16B/lane. LDS dest = wave-uniform base + lane*16.
__device__ inline void async_copy16(const bf16_t* gsrc, bf16_t* lds_dst) {
  __builtin_amdgcn_global_load_lds(
      (const __attribute__((address_space(1))) uint32_t*)(const void*)gsrc,
      (__attribute__((address_space(3))) uint32_t*)(void*)lds_dst,
      16, 0, 0);
}

// ---------------------------------------------------------------------------
// Merged prep: blocks [0,2048) convx; [2048,5120) transpose w_qkv;
// [5120,6144) transpose w_out. Transpose: float4 read, bf16x4 write. (R21)
// ---------------------------------------------------------------------------
__global__ __launch_bounds__(256) void prep_kernel(
    const float* __restrict__ x, const float* __restrict__ wq,
    const float* __restrict__ wo, bf16_t* __restrict__ xb,
    bf16_t* __restrict__ wqkvT, bf16_t* __restrict__ woutT) {
  __shared__ bf16_t tile[32][33];
  const int bid = blockIdx.x;
  if (bid < 2048) {
    const int i = bid * 256 + threadIdx.x;  // < 524288
    const float4* s = (const float4*)x;
    float4 a = s[i * 2], b = s[i * 2 + 1];
    bf16x8 o;
    o[0] = (bf16_t)a.x; o[1] = (bf16_t)a.y; o[2] = (bf16_t)a.z; o[3] = (bf16_t)a.w;
    o[4] = (bf16_t)b.x; o[5] = (bf16_t)b.y; o[6] = (bf16_t)b.z; o[7] = (bf16_t)b.w;
    ((bf16x8*)xb)[i] = o;
    return;
  }
  const bool isq = bid < 5120;
  const int id = isq ? bid - 2048 : bid - 5120;
  const int C = isq ? 3072 : 1024;
  const int R = 1024;
  const int nbx = isq ? 96 : 32;
  const float* in = isq ? wq : wo;
  bf16_t* out = isq ? wqkvT : woutT;
  const int c0 = (id % nbx) * 32, r0 = (id / nbx) * 32;
  const int tx4 = threadIdx.x & 7;   // col group (4 cols each)
  const int ty = threadIdx.x >> 3;   // row [0,32)
  {
    const float4 ld =
        *(const float4*)&in[(size_t)(r0 + ty) * C + c0 + tx4 * 4];
    tile[ty][tx4 * 4 + 0] = (bf16_t)ld.x;
    tile[ty][tx4 * 4 + 1] = (bf16_t)ld.y;
    tile[ty][tx4 * 4 + 2] = (bf16_t)ld.z;
    tile[ty][tx4 * 4 + 3] = (bf16_t)ld.w;
  }
  __syncthreads();
  {
    bf16x4 w;
    w[0] = tile[tx4 * 4 + 0][ty];
    w[1] = tile[tx4 * 4 + 1][ty];
    w[2] = tile[tx4 * 4 + 2][ty];
    w[3] = tile[tx4 * 4 + 3][ty];
    *(bf16x4*)&out[(size_t)(c0 + ty) * R + r0 + tx4 * 4] = w;
  }
}

// ---------------------------------------------------------------------------
// C[M,N] = A[M,K] @ Bt[N,K]^T + bias[N]. bf16 in; OUT_F32 selects store type.
// BM=BN=128, BK=64, 4 waves 2x2. global_load_lds staging with per-lane
// pre-swizzled SOURCE (chunk cs = cl ^ rl), linear LDS dest; ds_read at
// chunk (h*4+quad)^(row&7) -> 2-way bank aliasing (free). 16 K-iters. (R18)
// ---------------------------------------------------------------------------
template <bool OUT_F32>
__global__ __launch_bounds__(256, 3) void gemm_bt_kernel(
    const bf16_t* __restrict__ A, const bf16_t* __restrict__ Bt,
    const float* __restrict__ bias, void* __restrict__ Cv, int M, int N,
    int K) {
  __shared__ __align__(16) bf16_t sA[128 * 64];  // 16 KB
  __shared__ __align__(16) bf16_t sB[128 * 64];  // 16 KB
  const int tid = threadIdx.x;
  const int wave = tid >> 6, lane = tid & 63;
  const int quad = lane >> 4, l16 = lane & 15;
  const int wm = (wave >> 1) * 64, wn = (wave & 1) * 64;
  const int bm = blockIdx.y * 128, bn = blockIdx.x * 128;

  const int rl = lane >> 3, cl = lane & 7;
  const int srow = wave * 32;
  const bf16_t* gA =
      A + (size_t)(bm + srow + rl) * K + (size_t)((cl ^ rl) << 3);
  const bf16_t* gB =
      Bt + (size_t)(bn + srow + rl) * K + (size_t)((cl ^ rl) << 3);
  bf16_t* lA = sA + srow * 64;
  bf16_t* lB = sB + srow * 64;

  f32x4 acc[4][4] = {};

  for (int k0 = 0; k0 < K; k0 += 64) {
    __syncthreads();
#pragma unroll
    for (int c = 0; c < 4; c++) {
      async_copy16(gA + (size_t)(c * 8) * K + k0, lA + c * 512);
      async_copy16(gB + (size_t)(c * 8) * K + k0, lB + c * 512);
    }
    __syncthreads();

#pragma unroll
    for (int h = 0; h < 2; h++) {
      bf16x8 af[4], bfr[4];
#pragma unroll
      for (int i = 0; i < 4; i++) {
        const int row = wm + i * 16 + l16;
        af[i] = *(const bf16x8*)&sA[row * 64 +
                                    (((h * 4 + quad) ^ (row & 7)) << 3)];
      }
#pragma unroll
      for (int j = 0; j < 4; j++) {
        const int row = wn + j * 16 + l16;
        bfr[j] = *(const bf16x8*)&sB[row * 64 +
                                     (((h * 4 + quad) ^ (row & 7)) << 3)];
      }
#pragma unroll
      for (int i = 0; i < 4; i++)
#pragma unroll
        for (int j = 0; j < 4; j++)
          acc[i][j] = __builtin_amdgcn_mfma_f32_16x16x32_bf16(
              af[i], bfr[j], acc[i][j], 0, 0, 0);
    }
  }

#pragma unroll
  for (int j = 0; j < 4; j++) {
    const int col = bn + wn + j * 16 + l16;
    const float bv = bias[col];
#pragma unroll
    for (int i = 0; i < 4; i++) {
#pragma unroll
      for (int r = 0; r < 4; r++) {
        const int row = bm + wm + i * 16 + quad * 4 + r;
        const float v = acc[i][j][r] + bv;
        if (OUT_F32)
          ((float*)Cv)[(size_t)row * N + col] = v;
        else
          ((bf16_t*)Cv)[(size_t)row * N + col] = (bf16_t)v;
      }
    }
  }
}

// ---------------------------------------------------------------------------
// gemm2: BM=64, BN=128, BK=64 (f32 out), R18 swizzle scheme. Grid
// (N/128, M/64) = 512 blocks = 2 blocks/CU. sA 8KB + sB 16KB = 24KB. (R19)
// ---------------------------------------------------------------------------
__global__ __launch_bounds__(256) void gemm_bt64_kernel(
    const bf16_t* __restrict__ A, const bf16_t* __restrict__ Bt,
    const float* __restrict__ bias, float* __restrict__ C, int M, int N,
    int K) {
  __shared__ __align__(16) bf16_t sA[64 * 64];   // 8 KB
  __shared__ __align__(16) bf16_t sB[128 * 64];  // 16 KB
  const int tid = threadIdx.x;
  const int wave = tid >> 6, lane = tid & 63;
  const int quad = lane >> 4, l16 = lane & 15;
  const int wm = (wave >> 1) * 32, wn = (wave & 1) * 64;
  const int bm = blockIdx.y * 64, bn = blockIdx.x * 128;

  const int rl = lane >> 3, cl = lane & 7;
  const bf16_t* gA =
      A + (size_t)(bm + wave * 16 + rl) * K + (size_t)((cl ^ rl) << 3);
  bf16_t* lA = sA + (wave * 16) * 64;
  const bf16_t* gB =
      Bt + (size_t)(bn + wave * 32 + rl) * K + (size_t)((cl ^ rl) << 3);
  bf16_t* lB = sB + (wave * 32) * 64;

  f32x4 acc[2][4] = {};

  for (int k0 = 0; k0 < K; k0 += 64) {
    __syncthreads();
#pragma unroll
    for (int c = 0; c < 2; c++)
      async_copy16(gA + (size_t)(c * 8) * K + k0, lA + c * 512);
#pragma unroll
    for (int c = 0; c < 4; c++)
      async_copy16(gB + (size_t)(c * 8) * K + k0, lB + c * 512);
    __syncthreads();

#pragma unroll
    for (int h = 0; h < 2; h++) {
      bf16x8 af[2], bfr[4];
#pragma unroll
      for (int i = 0; i < 2; i++) {
        const int row = wm + i * 16 + l16;
        af[i] = *(const bf16x8*)&sA[row * 64 +
                                    (((h * 4 + quad) ^ (row & 7)) << 3)];
      }
#pragma unroll
      for (int j = 0; j < 4; j++) {
        const int row = wn + j * 16 + l16;
        bfr[j] = *(const bf16x8*)&sB[row * 64 +
                                     (((h * 4 + quad) ^ (row & 7)) << 3)];
      }
#pragma unroll
      for (int i = 0; i < 2; i++)
#pragma unroll
        for (int j = 0; j < 4; j++)
          acc[i][j] = __builtin_amdgcn_mfma_f32_16x16x32_bf16(
              af[i], bfr[j], acc[i][j], 0, 0, 0);
    }
  }

#pragma unroll
  for (int j = 0; j < 4; j++) {
    const int col = bn + wn + j * 16 + l16;
    const float bv = bias[col];
#pragma unroll
    for (int i = 0; i < 2; i++) {
#pragma unroll
      for (int r = 0; r < 4; r++) {
        const int row = bm + wm + i * 16 + quad * 4 + r;
        C[(size_t)row * N + col] = acc[i][j][r] + bv;
      }
    }
  }
}

// ---------------------------------------------------------------------------
// R25 attention = R22 (proven): R14 walk with K staged via global_load_lds.
// S^T = K@Q^T (16x16x32), P in registers as the K=16 MFMA A-fragment;
// O += P@V via mfma_f32_16x16x16. Double-buffered sK/sVt, ONE barrier per
// 64-key tile. Fixed-M softmax. Main loop branchless; diag hoisted.
// sK : (t,d) slot g^(t&7) holds global chunk g       [8 KB/buf]
//      staged: lane r*8+c of 8-row call writes linear slot c from global
//      chunk c^r (t&7 == r) -> identical layout, no reg round-trip.
// sVt: (d,t) at d*64 + ((kq ^ (d&15))<<2)            [8 KB/buf, reg path]
// K loads for tile kt+1 issue AFTER barrier(kt) into the free buffer
// (readers of it finished before the barrier) and drain at barrier(kt+1).
// Balance: X remapped so each CU's 4 resident blocks have sum(X)==62.
// ---------------------------------------------------------------------------
__global__ __launch_bounds__(256, 4) void attn_kernel(
    const bf16_t* __restrict__ qkv, bf16_t* __restrict__ Y) {
  constexpr int T = 2048, C3 = 3072;
  constexpr float CSC = 0.18033688f;  // 0.125 * log2(e)
  constexpr float MB = 20.0f;
  __shared__ __align__(16) bf16_t sK[2][64 * 64];
  __shared__ __align__(16) bf16_t sVt[2][64 * 64];

  const int tid = threadIdx.x;
  const int wave = tid >> 6, lane = tid & 63;
  const int quad = lane >> 4, l16 = lane & 15;
  const int bh = blockIdx.y;
  // causal-depth balance remap (bijective in bx for each bh):
  const int flip = (bh >> 3) & 1;
  const int vv = ((int)blockIdx.x + ((bh >> 4) & 1) * 8) & 31;
  const int X = flip ? (31 - vv) : vv;
  const int q0 = X * 64;
  const int b = bh >> 4, h = bh & 15;
  const size_t base = (size_t)b * T * C3 + (size_t)h * 64;

  // Q as B-operand: lane n=l16=query, k = quad*8+j
  const int qrow = q0 + wave * 16 + l16;
  const bf16x8 qf0 = *(const bf16x8*)&qkv[base + (size_t)qrow * C3 + quad * 8];
  const bf16x8 qf1 =
      *(const bf16x8*)&qkv[base + (size_t)qrow * C3 + 32 + quad * 8];

  f32x4 o[4] = {};   // O: lane holds rows (query) quad*4+r, col d = n16*16+l16
  f32x4 l4 = {0.f, 0.f, 0.f, 0.f};  // 4 parallel partial-sum chains

  // K staging via gload_lds: wave covers key rows [16w,16w+16), 2 calls x
  // 8 rows. lane r*8+c -> LDS row 16w+8q+r slot c, source chunk c^r.
  const int krr = lane >> 3, kcc = lane & 7;
  const bf16_t* gKa =
      &qkv[base + (size_t)(16 * wave + krr) * C3 + 1024 + ((kcc ^ krr) << 3)];
  bf16_t* const lK0 = (bf16_t*)&sK[0][(16 * wave) * 64];
  bf16_t* const lK1 = (bf16_t*)&sK[1][(16 * wave) * 64];

  // V staging: (kq = tid>>4 key-quad, dq = tid&15 d-quad), reg path
  const int kq = tid >> 4, dq = tid & 15;
  const bf16_t* gV = &qkv[base + (size_t)(4 * kq) * C3 + 2048 + dq * 4];

  // prologue: issue tile-0 K loads; prefetch tile-0 V regs
  async_copy16(gKa, lK0);
  async_copy16(gKa + (size_t)8 * C3, lK0 + 8 * 64);
  bf16x4 vA0 = *(const bf16x4*)gV;
  bf16x4 vA1 = *(const bf16x4*)(gV + C3);
  bf16x4 vA2 = *(const bf16x4*)(gV + 2 * C3);
  bf16x4 vA3 = *(const bf16x4*)(gV + 3 * C3);

  // ---- main loop: tiles 0..X-1, all keys < all queries: branch-free ----
  for (int kt = 0; kt < X; kt++) {
    const int p = kt & 1;
    // stage V (4 b64, key-quad granules)
#pragma unroll
    for (int i = 0; i < 4; i++) {
      const int d = dq * 4 + i;
      bf16x4 w;
      w[0] = vA0[i]; w[1] = vA1[i]; w[2] = vA2[i]; w[3] = vA3[i];
      *(bf16x4*)&sVt[p][d * 64 + ((kq ^ (d & 15)) << 2)] = w;
    }
    // prefetch next V tile (kt+1 <= X always valid); overlaps compute
    {
      const size_t off = (size_t)(kt + 1) * 64 * C3;
      vA0 = *(const bf16x4*)(gV + off);
      vA1 = *(const bf16x4*)(gV + off + C3);
      vA2 = *(const bf16x4*)(gV + off + 2 * C3);
      vA3 = *(const bf16x4*)(gV + off + 3 * C3);
    }
    __syncthreads();  // drains K gload_lds(kt) + sVt[p] visible + buf 1-p free

    // issue K loads for tile kt+1 into the now-free buffer; they overlap
    // the whole compute phase and drain at the next barrier.
    {
      const size_t off = (size_t)(kt + 1) * 64 * C3;
      bf16_t* const lKn = p ? lK0 : lK1;
      async_copy16(gKa + off, lKn);
      async_copy16(gKa + off + (size_t)8 * C3, lKn + 8 * 64);
    }

#pragma unroll
    for (int j = 0; j < 4; j++) {
      // S^T j-tile: A = K-frag (lane m=l16 -> key j*16+l16), B = Q-frag
      const int trow = j * 16 + l16;
      bf16x8 kf0 =
          *(const bf16x8*)&sK[p][trow * 64 + ((quad ^ (trow & 7)) << 3)];
      bf16x8 kf1 =
          *(const bf16x8*)&sK[p][trow * 64 + (((4 + quad) ^ (trow & 7)) << 3)];
      f32x4 s2 = {};
      __builtin_amdgcn_s_setprio(1);
      s2 = __builtin_amdgcn_mfma_f32_16x16x32_bf16(kf0, qf0, s2, 0, 0, 0);
      s2 = __builtin_amdgcn_mfma_f32_16x16x32_bf16(kf1, qf1, s2, 0, 0, 0);
      __builtin_amdgcn_s_setprio(0);
#pragma unroll
      for (int r = 0; r < 4; r++) s2[r] = EXP2F(fmaf(s2[r], CSC, -MB));
      l4 += s2;  // 4 parallel chains
      bf16x4 pb;
      pb[0] = (bf16_t)s2[0]; pb[1] = (bf16_t)s2[1];
      pb[2] = (bf16_t)s2[2]; pb[3] = (bf16_t)s2[3];
      union { bf16x4 bv; short4v sv; } u;
      u.bv = pb;
      const short4v pa = u.sv;
      __builtin_amdgcn_s_setprio(1);
#pragma unroll
      for (int n16 = 0; n16 < 4; n16++) {
        const int d = n16 * 16 + l16;
        const short4v vf = *(const short4v*)&sVt[p][d * 64 +
                                                    (((j * 4 + quad) ^ (d & 15))
                                                     << 2)];
        o[n16] =
            __builtin_amdgcn_mfma_f32_16x16x16bf16_1k(pa, vf, o[n16], 0, 0, 0);
      }
      __builtin_amdgcn_s_setprio(0);
    }
  }

  // ---- diagonal tile kt == X (hoisted; j-skip + diag mask). K for this
  // tile was issued at iter X-1 (or the prologue when X==0). ----
  {
    const int p = X & 1;
#pragma unroll
    for (int i = 0; i < 4; i++) {
      const int d = dq * 4 + i;
      bf16x4 w;
      w[0] = vA0[i]; w[1] = vA1[i]; w[2] = vA2[i]; w[3] = vA3[i];
      *(bf16x4*)&sVt[p][d * 64 + ((kq ^ (d & 15)) << 2)] = w;
    }
    __syncthreads();  // drains K gload_lds(X); sVt[p] visible

#pragma unroll
    for (int j = 0; j < 4; j++) {
      if (j > wave) continue;  // wave-uniform; P would be all-zero
      const int trow = j * 16 + l16;
      bf16x8 kf0 =
          *(const bf16x8*)&sK[p][trow * 64 + ((quad ^ (trow & 7)) << 3)];
      bf16x8 kf1 =
          *(const bf16x8*)&sK[p][trow * 64 + (((4 + quad) ^ (trow & 7)) << 3)];
      f32x4 s2 = {};
      __builtin_amdgcn_s_setprio(1);
      s2 = __builtin_amdgcn_mfma_f32_16x16x32_bf16(kf0, qf0, s2, 0, 0, 0);
      s2 = __builtin_amdgcn_mfma_f32_16x16x32_bf16(kf1, qf1, s2, 0, 0, 0);
      __builtin_amdgcn_s_setprio(0);
      const bool diag = (j == wave);
#pragma unroll
      for (int r = 0; r < 4; r++) {
        float pv = EXP2F(fmaf(s2[r], CSC, -MB));
        if (diag && (quad * 4 + r > l16)) pv = 0.f;
        s2[r] = pv;
      }
      l4 += s2;
      bf16x4 pb;
      pb[0] = (bf16_t)s2[0]; pb[1] = (bf16_t)s2[1];
      pb[2] = (bf16_t)s2[2]; pb[3] = (bf16_t)s2[3];
      union { bf16x4 bv; short4v sv; } u;
      u.bv = pb;
      const short4v pa = u.sv;
      __builtin_amdgcn_s_setprio(1);
#pragma unroll
      for (int n16 = 0; n16 < 4; n16++) {
        const int d = n16 * 16 + l16;
        const short4v vf = *(const short4v*)&sVt[p][d * 64 +
                                                    (((j * 4 + quad) ^ (d & 15))
                                                     << 2)];
        o[n16] =
            __builtin_amdgcn_mfma_f32_16x16x16bf16_1k(pa, vf, o[n16], 0, 0, 0);
      }
      __builtin_amdgcn_s_setprio(0);
    }
  }

  // epilogue: complete l across quads (2 shuffles), redistribute, store
  float l_acc = (l4[0] + l4[1]) + (l4[2] + l4[3]);
  l_acc += __shfl_xor(l_acc, 16);
  l_acc += __shfl_xor(l_acc, 32);
#pragma unroll
  for (int r = 0; r < 4; r++) {
    const float lr = __shfl(l_acc, quad * 4 + r);
    const float inv = 1.0f / lr;
    const int row = q0 + wave * 16 + quad * 4 + r;
#pragma unroll
    for (int n16 = 0; n16 < 4; n16++)
      Y[((size_t)b * T + row) * 1024 + h * 64 + n16 * 16 + l16] =
          (bf16_t)(o[n16][r] * inv);
  }
}

// ---------------------------------------------------------------------------
extern "C" void kernel_launch(void* const* d_in, const int* in_sizes, int n_in,
                              void* d_out, int out_size, void* d_ws,
                              size_t ws_size, hipStream_t stream) {
  const float* x = nullptr;
  const float* w_qkv = nullptr;
  const float* b_qkv = nullptr;
  const float* w_out = nullptr;
  const float* b_out = nullptr;
  for (int i = 0; i < n_in; i++) {
    switch (in_sizes[i]) {
      case 4194304: x = (const float*)d_in[i]; break;
      case 3145728: w_qkv = (const float*)d_in[i]; break;
      case 3072:    b_qkv = (const float*)d_in[i]; break;
      case 1048576: w_out = (const float*)d_in[i]; break;
      case 1024:    b_out = (const float*)d_in[i]; break;
      default: break;
    }
  }
  float* out = (float*)d_out;  // FP32 output

  bf16_t* xb = (bf16_t*)d_ws;
  bf16_t* wqkvT = xb + (size_t)4194304;
  bf16_t* woutT = wqkvT + (size_t)3145728;
  bf16_t* qkv = woutT + (size_t)1048576;
  bf16_t* Y = qkv + (size_t)12582912;

  prep_kernel<<<6144, 256, 0, stream>>>(x, w_qkv, w_out, xb, wqkvT, woutT);
  gemm_bt_kernel<false><<<dim3(24, 32), 256, 0, stream>>>(
      xb, wqkvT, b_qkv, (void*)qkv, 4096, 3072, 1024);
  attn_kernel<<<dim3(32, 32), 256, 0, stream>>>(qkv, Y);
  gemm_bt64_kernel<<<dim3(8, 64), 256, 0, stream>>>(
      Y, woutT, b_out, out, 4096, 1024, 1024);
}